// Round 3
// baseline (204.504 us; speedup 1.0000x reference)
//
#include <hip/hip_runtime.h>
#include <hip/hip_bf16.h>
#include <math.h>

#define ICH   3
#define OCH   16
#define ID    18
#define IH    34
#define IW    34
#define OD    16
#define OH    32
#define OW    32
#define NB    128
#define SPATIAL  (OD * OH * OW)     // 16384 per (b,c)
#define EPSV     1e-5f

// INSTRUMENTATION ROUND: norm_max body repeated NREP times with rotated
// segment mapping (bijective each rep, idempotent writes). Purpose: force
// norm_max above the top-5 duration cutoff so we finally get its counter
// row (VGPR/FETCH/WRITE/VALUBusy/Occupancy). dur/NREP ~= true N.
// NEXT ROUND: set NREP back to 1.
#define NREP  6

typedef __fp16 fp16x2 __attribute__((ext_vector_type(2)));

// Tiny pre-pass: transpose weights [oc][k=81] -> [k=81][oc=16] so the conv's
// per-(ic,kd,kh) weight group (48 floats) is CONTIGUOUS -> 3x s_load_dwordx16
// instead of 48 scattered 4B s_load_dword.
__global__ void transpose_w_kernel(const float* __restrict__ cw,
                                   float* __restrict__ wt) {
    const int i = blockIdx.x * 256 + threadIdx.x;
    if (i < OCH * 81) {
        const int c = i / 81, k = i - c * 81;
        wt[k * OCH + c] = cw[i];
    }
}

// ===== conv v9 (UNCHANGED from R2): channel-last y[b][s][c16] stores.
// Known cost vs channel-major conv: +4.3us (56 VGPR vs 48). Kept because
// the contiguous-norm probe needs this layout; revisit after N is known.
// Do NOT: raise min-waves (R2/R3 spill), LDS-stage x (R1-R8), MFMA im2col
// (R13), fp16 x staging (R5), grid caps/fusion (R11), tile shrink (R8).
__global__ __launch_bounds__(256, 2) void conv_stats_kernel(
    const float* __restrict__ x, const float* __restrict__ wt,
    const float* __restrict__ cb, const float* __restrict__ mult,
    unsigned short* __restrict__ y, float* __restrict__ stats)
{
    __shared__ float wsum[4][OCH], wsq[4][OCH];

    const int blk = blockIdx.x;
    const int b = blk >> 4;
    const int d = blk & 15;
    const int tid = threadIdx.x;

    const int h  = tid >> 3;        // 0..31
    const int wq = (tid & 7) << 2;  // 0,4,...,28

    float acc[OCH][4];
#pragma unroll
    for (int c = 0; c < OCH; c++) {
        const float bv = cb[c];
        acc[c][0] = bv; acc[c][1] = bv; acc[c][2] = bv; acc[c][3] = bv;
    }

    for (int ic = 0; ic < ICH; ic++) {
        for (int kd = 0; kd < 3; kd++) {
            const float* plane = x + ((size_t)(b * ICH + ic) * ID + (d + kd)) * (IH * IW);
            const float* wgrp  = wt + (ic * 3 + kd) * 3 * 48;   // 3 kh x 48 floats
#pragma unroll
            for (int kh = 0; kh < 3; kh++) {
                const float* row = plane + (size_t)(h + kh) * IW + wq;
                const float4 v0 = *(const float4*)row;
                const float2 v1 = *(const float2*)(row + 4);
                float in[6];
                in[0] = v0.x; in[1] = v0.y; in[2] = v0.z; in[3] = v0.w;
                in[4] = v1.x; in[5] = v1.y;
                const float* wrow = wgrp + kh * 48;             // contiguous 48
#pragma unroll
                for (int kw = 0; kw < 3; kw++) {
#pragma unroll
                    for (int c = 0; c < OCH; c++) {
                        const float wv = wrow[kw * OCH + c];    // s_load_dwordx16 path
                        acc[c][0] = fmaf(in[kw + 0], wv, acc[c][0]);
                        acc[c][1] = fmaf(in[kw + 1], wv, acc[c][1]);
                        acc[c][2] = fmaf(in[kw + 2], wv, acc[c][2]);
                        acc[c][3] = fmaf(in[kw + 3], wv, acc[c][3]);
                    }
                }
            }
        }
    }

    // ---- multiplier fold + stats (numerics identical to baseline) ----
    float ssum[OCH], ssq[OCH];
#pragma unroll
    for (int c = 0; c < OCH; c++) {
        const float m = mult[c];
        const float o0 = acc[c][0] * m, o1 = acc[c][1] * m;
        const float o2 = acc[c][2] * m, o3 = acc[c][3] * m;
        ssum[c] = (o0 + o1) + (o2 + o3);
        ssq[c]  = (o0 * o0 + o1 * o1) + (o2 * o2 + o3 * o3);
        acc[c][0] = o0; acc[c][1] = o1; acc[c][2] = o2; acc[c][3] = o3;
    }

    // ---- channel-last packed store: y[b][s][c16], 4 positions x 32 B ----
    {
        const int s0 = d * (OH * OW) + h * OW + wq;     // 4 consecutive positions
        unsigned short* yb = y + ((size_t)b * SPATIAL + s0) * OCH;
#pragma unroll
        for (int j = 0; j < 4; j++) {
            union { fp16x2 h; unsigned int u; } pk;
            uint4 q0, q1;
            pk.h = __builtin_amdgcn_cvt_pkrtz(acc[0][j],  acc[1][j]);  q0.x = pk.u;
            pk.h = __builtin_amdgcn_cvt_pkrtz(acc[2][j],  acc[3][j]);  q0.y = pk.u;
            pk.h = __builtin_amdgcn_cvt_pkrtz(acc[4][j],  acc[5][j]);  q0.z = pk.u;
            pk.h = __builtin_amdgcn_cvt_pkrtz(acc[6][j],  acc[7][j]);  q0.w = pk.u;
            pk.h = __builtin_amdgcn_cvt_pkrtz(acc[8][j],  acc[9][j]);  q1.x = pk.u;
            pk.h = __builtin_amdgcn_cvt_pkrtz(acc[10][j], acc[11][j]); q1.y = pk.u;
            pk.h = __builtin_amdgcn_cvt_pkrtz(acc[12][j], acc[13][j]); q1.z = pk.u;
            pk.h = __builtin_amdgcn_cvt_pkrtz(acc[14][j], acc[15][j]); q1.w = pk.u;
            *(uint4*)(yb + (size_t)j * OCH)     = q0;
            *(uint4*)(yb + (size_t)j * OCH + 8) = q1;
        }
    }

    // ---- block reduction of stats, per-block partial write (no atomics) ----
#pragma unroll
    for (int c = 0; c < OCH; c++) {
        for (int off = 32; off > 0; off >>= 1) {
            ssum[c] += __shfl_down(ssum[c], off);
            ssq[c]  += __shfl_down(ssq[c], off);
        }
    }
    const int wave = tid >> 6, lane = tid & 63;
    if (lane == 0) {
#pragma unroll
        for (int c = 0; c < OCH; c++) { wsum[wave][c] = ssum[c]; wsq[wave][c] = ssq[c]; }
    }
    __syncthreads();
    if (tid < OCH) {
        float s = 0.0f, q = 0.0f;
#pragma unroll
        for (int k = 0; k < 4; k++) { s += wsum[k][tid]; q += wsq[k][tid]; }
        const int sbase = ((b * OD + d) * OCH + tid) * 2;
        stats[sbase + 0] = s;
        stats[sbase + 1] = q;
    }
}

// ===== per-(b,c) norm params: {A = rs*m, B = -mean*rs*m, L = -|m|, H = +|m|}
// so the hot kernel does out_c = clamp(v*A + B, L, H) per element.
__global__ void params_kernel(const float* __restrict__ stats,
                              const float* __restrict__ mult,
                              float4* __restrict__ prm)
{
    const int i = blockIdx.x * 256 + threadIdx.x;   // (b,c) pair
    if (i < NB * OCH) {
        const int b = i >> 4, c = i & 15;
        float s = 0.0f, q = 0.0f;
        for (int dd = 0; dd < OD; dd++) {
            s += stats[((b * OD + dd) * OCH + c) * 2 + 0];
            q += stats[((b * OD + dd) * OCH + c) * 2 + 1];
        }
        const float mean = s * (1.0f / (float)SPATIAL);
        float var = q * (1.0f / (float)SPATIAL) - mean * mean;
        var = fmaxf(var, 0.0f);
        const float rs = rsqrtf(var + EPSV);
        const float m  = mult[c];
        float4 p;
        p.x = rs * m;             // A
        p.y = -mean * rs * m;     // B
        p.z = -fabsf(m);          // L
        p.w =  fabsf(m);          // H
        prm[i] = p;
    }
}

// ===== norm_max v4-PROBE: contiguous reads, LB(256,2) (no spill possible:
// VGPR budget 256), params via wave-uniform loads (s_load path, no VGPR
// staging), NREP bijectively-rotated passes so the dispatch surfaces in
// the top-5 counter table. dur/NREP ~= true single-pass N.
__global__ __launch_bounds__(256, 2) void norm_max_kernel(
    const unsigned short* __restrict__ y, const float4* __restrict__ prm,
    float* __restrict__ out)
{
    const int blk = blockIdx.x;     // NB*32 = 4096
    const int b   = blk >> 5;
    const int seg0 = blk & 31;
    const int tid = threadIdx.x;

    const float4* pb = prm + b * OCH;            // wave-uniform -> s_load

#pragma unroll 1
    for (int rep = 0; rep < NREP; rep++) {
        const int seg = (seg0 + rep * 5) & 31;   // bijection per rep
        const int s = seg * 512 + tid * 2;       // 2 positions
        const unsigned short* yb = y + ((size_t)b * SPATIAL + s) * OCH;

        const uint4 v0 = *(const uint4*)(yb);        // pos0 ch0-7
        const uint4 v1 = *(const uint4*)(yb + 8);    // pos0 ch8-15
        const uint4 v2 = *(const uint4*)(yb + 16);   // pos1 ch0-7
        const uint4 v3 = *(const uint4*)(yb + 24);   // pos1 ch8-15

        float m0 = -INFINITY, m1 = -INFINITY;

#define DO_PAIR(u_, c0_, mx_)                                              \
        {                                                                  \
            const float4 pA = pb[c0_];                                     \
            const float4 pB = pb[c0_ + 1];                                 \
            union { unsigned int u; __fp16 h[2]; } a_; a_.u = (u_);        \
            float f0 = fmaf((float)a_.h[0], pA.x, pA.y);                   \
            float f1 = fmaf((float)a_.h[1], pB.x, pB.y);                   \
            f0 = fminf(fmaxf(f0, pA.z), pA.w);                             \
            f1 = fminf(fmaxf(f1, pB.z), pB.w);                             \
            mx_ = fmaxf(mx_, fmaxf(f0, f1));                               \
        }

        DO_PAIR(v0.x,  0, m0) DO_PAIR(v0.y,  2, m0)
        DO_PAIR(v0.z,  4, m0) DO_PAIR(v0.w,  6, m0)
        DO_PAIR(v1.x,  8, m0) DO_PAIR(v1.y, 10, m0)
        DO_PAIR(v1.z, 12, m0) DO_PAIR(v1.w, 14, m0)

        DO_PAIR(v2.x,  0, m1) DO_PAIR(v2.y,  2, m1)
        DO_PAIR(v2.z,  4, m1) DO_PAIR(v2.w,  6, m1)
        DO_PAIR(v3.x,  8, m1) DO_PAIR(v3.y, 10, m1)
        DO_PAIR(v3.z, 12, m1) DO_PAIR(v3.w, 14, m1)
#undef DO_PAIR

        float2 o; o.x = m0; o.y = m1;
        *(float2*)&out[(size_t)b * SPATIAL + s] = o;
    }
}

extern "C" void kernel_launch(void* const* d_in, const int* in_sizes, int n_in,
                              void* d_out, int out_size, void* d_ws, size_t ws_size,
                              hipStream_t stream) {
    const float* x    = (const float*)d_in[0];
    const float* cw   = (const float*)d_in[1];
    const float* cb   = (const float*)d_in[2];
    const float* mult = (const float*)d_in[3];
    float* out = (float*)d_out;

    // ws: y fp16 channel-last (64 MB) | stats partials (256 KB) | prm (8 KB) | wt (5.2 KB)
    unsigned short* y = (unsigned short*)d_ws;
    float* stats = (float*)((char*)d_ws + (size_t)NB * OCH * SPATIAL * sizeof(unsigned short));
    float4* prm  = (float4*)(stats + NB * OD * OCH * 2);
    float* wt    = (float*)(prm + NB * OCH);

    transpose_w_kernel<<<6, 256, 0, stream>>>(cw, wt);
    conv_stats_kernel<<<NB * 16, 256, 0, stream>>>(x, wt, cb, mult, y, stats);
    params_kernel<<<8, 256, 0, stream>>>(stats, mult, prm);
    norm_max_kernel<<<NB * 32, 256, 0, stream>>>(y, prm, out);
}

// Round 4
// 148.596 us; speedup vs baseline: 1.3762x; 1.3762x over previous
//
#include <hip/hip_runtime.h>
#include <hip/hip_bf16.h>
#include <math.h>

#define ICH   3
#define OCH   16
#define ID    18
#define IH    34
#define IW    34
#define OD    16
#define OH    32
#define OW    32
#define NB    128
#define SPATIAL  (OD * OH * OW)     // 16384 per (b,c)
#define EPSV     1e-5f

typedef __fp16 fp16x2 __attribute__((ext_vector_type(2)));

// Budget (R3 probe): conv 63.5 | norm 11-12 (roofline) | tiny 2 | fixed
// harness overhead ~67 (constant across R0-R3, not addressable). Only conv
// is a lever: 63.5us vs 34.6us FMA floor, stall-bound at 2.9 waves/SIMD
// (64-float acc lives in AGPRs -> ~112 regs/wave). This round: half-split.

// Tiny pre-pass: transpose weights [oc][k=81] -> [k=81][oc=16] so the conv's
// per-(ic,kd,kh) weight group (48 floats) is CONTIGUOUS -> s_load_dwordx8/16.
__global__ void transpose_w_kernel(const float* __restrict__ cw,
                                   float* __restrict__ wt) {
    const int i = blockIdx.x * 256 + threadIdx.x;
    if (i < OCH * 81) {
        const int c = i / 81, k = i - c * 81;
        wt[k * OCH + c] = cw[i];
    }
}

// ===== conv v10: HALF-SPLIT. Each block does 8 of the 16 channels for one
// (b,d) slice -> acc 32 floats (was 64) -> ~80 regs/wave -> 6 waves/SIMD
// (was 2.9). LB(256,4) now safe (needs ~80 <= 128 budget; the old R2/R3
// "min-waves spill" was the 64-float-acc version). Grid 4096 with XCD
// pairing: halves of one (b,d) are 8 blocks apart -> same XCD L2 -> the
// duplicated x-row reads hit L2. Per-channel FMA order unchanged -> same
// numerics. y store: channel-major (R1 path, 48-VGPR store cost).
// Do NOT: LDS-stage x (R1-R8), MFMA im2col (R13), fp16 x staging (R5).
__global__ __launch_bounds__(256, 4) void conv_stats_kernel(
    const float* __restrict__ x, const float* __restrict__ wt,
    const float* __restrict__ cb, const float* __restrict__ mult,
    unsigned short* __restrict__ y, float* __restrict__ stats)
{
    __shared__ float wsum[4][8], wsq[4][8];

    const int blk  = blockIdx.x;              // 0..4095
    const int pid  = (blk >> 4) * 8 + (blk & 7);   // (b,d) id, 0..2047
    const int half = (blk >> 3) & 1;               // paired 8 apart (same XCD)
    const int b = pid >> 4;
    const int d = pid & 15;
    const int tid = threadIdx.x;
    const int c0 = half * 8;

    const int h  = tid >> 3;        // 0..31
    const int wq = (tid & 7) << 2;  // 0,4,...,28

    float acc[8][4];
#pragma unroll
    for (int c = 0; c < 8; c++) {
        const float bv = cb[c0 + c];
        acc[c][0] = bv; acc[c][1] = bv; acc[c][2] = bv; acc[c][3] = bv;
    }

    for (int ic = 0; ic < ICH; ic++) {
        for (int kd = 0; kd < 3; kd++) {
            const float* plane = x + ((size_t)(b * ICH + ic) * ID + (d + kd)) * (IH * IW);
            const float* wgrp  = wt + (ic * 3 + kd) * 3 * 48;   // 3 kh x 48 floats
#pragma unroll
            for (int kh = 0; kh < 3; kh++) {
                const float* row = plane + (size_t)(h + kh) * IW + wq;
                const float4 v0 = *(const float4*)row;
                const float2 v1 = *(const float2*)(row + 4);
                float in[6];
                in[0] = v0.x; in[1] = v0.y; in[2] = v0.z; in[3] = v0.w;
                in[4] = v1.x; in[5] = v1.y;
                const float* wrow = wgrp + kh * 48;             // contiguous 48
#pragma unroll
                for (int kw = 0; kw < 3; kw++) {
#pragma unroll
                    for (int c = 0; c < 8; c++) {
                        const float wv = wrow[kw * OCH + c0 + c]; // s_load dwordx8
                        acc[c][0] = fmaf(in[kw + 0], wv, acc[c][0]);
                        acc[c][1] = fmaf(in[kw + 1], wv, acc[c][1]);
                        acc[c][2] = fmaf(in[kw + 2], wv, acc[c][2]);
                        acc[c][3] = fmaf(in[kw + 3], wv, acc[c][3]);
                    }
                }
            }
        }
    }

    // ---- multiplier fold, stats, fp16 store (channel-major, uint2) ----
    float ssum[8], ssq[8];
#pragma unroll
    for (int c = 0; c < 8; c++) {
        const float m = mult[c0 + c];
        const float o0 = acc[c][0] * m, o1 = acc[c][1] * m;
        const float o2 = acc[c][2] * m, o3 = acc[c][3] * m;
        ssum[c] = (o0 + o1) + (o2 + o3);
        ssq[c]  = (o0 * o0 + o1 * o1) + (o2 * o2 + o3 * o3);
        const size_t yi = ((size_t)(b * OCH + c0 + c) * OD + d) * (OH * OW) + h * OW + wq;
        union { fp16x2 h; unsigned int u; } p01, p23;
        p01.h = __builtin_amdgcn_cvt_pkrtz(o0, o1);
        p23.h = __builtin_amdgcn_cvt_pkrtz(o2, o3);
        uint2 pk; pk.x = p01.u; pk.y = p23.u;
        *(uint2*)&y[yi] = pk;
    }

    // ---- block reduction of stats, per-block partial write (no atomics) ----
#pragma unroll
    for (int c = 0; c < 8; c++) {
        for (int off = 32; off > 0; off >>= 1) {
            ssum[c] += __shfl_down(ssum[c], off);
            ssq[c]  += __shfl_down(ssq[c], off);
        }
    }
    const int wave = tid >> 6, lane = tid & 63;
    if (lane == 0) {
#pragma unroll
        for (int c = 0; c < 8; c++) { wsum[wave][c] = ssum[c]; wsq[wave][c] = ssq[c]; }
    }
    __syncthreads();
    if (tid < 8) {
        float s = 0.0f, q = 0.0f;
#pragma unroll
        for (int k = 0; k < 4; k++) { s += wsum[k][tid]; q += wsq[k][tid]; }
        const int sbase = ((b * OD + d) * OCH + c0 + tid) * 2;  // same layout as before
        stats[sbase + 0] = s;
        stats[sbase + 1] = q;
    }
}

// ===== per-(b,c) norm params: {A = rs*m, B = -mean*rs*m, L = -|m|, H = +|m|}
// so the hot kernel does out_c = clamp(v*A + B, L, H) per element.
__global__ void params_kernel(const float* __restrict__ stats,
                              const float* __restrict__ mult,
                              float4* __restrict__ prm)
{
    const int i = blockIdx.x * 256 + threadIdx.x;   // (b,c) pair
    if (i < NB * OCH) {
        const int b = i >> 4, c = i & 15;
        float s = 0.0f, q = 0.0f;
        for (int dd = 0; dd < OD; dd++) {
            s += stats[((b * OD + dd) * OCH + c) * 2 + 0];
            q += stats[((b * OD + dd) * OCH + c) * 2 + 1];
        }
        const float mean = s * (1.0f / (float)SPATIAL);
        float var = q * (1.0f / (float)SPATIAL) - mean * mean;
        var = fmaxf(var, 0.0f);
        const float rs = rsqrtf(var + EPSV);
        const float m  = mult[c];
        float4 p;
        p.x = rs * m;             // A
        p.y = -mean * rs * m;     // B
        p.z = -fabsf(m);          // L
        p.w =  fabsf(m);          // H
        prm[i] = p;
    }
}

// ===== norm_max (R1 version, measured ~11-12us = BW roofline; do not touch).
// 8 positions/thread via uint4, all 16 channel streams issued up-front.
__global__ __launch_bounds__(256, 4) void norm_max_kernel(
    const unsigned short* __restrict__ y, const float4* __restrict__ prm,
    float* __restrict__ out)
{
    const int blk = blockIdx.x;     // NB*8 = 1024
    const int b   = blk >> 3;
    const int seg = blk & 7;
    const int tid = threadIdx.x;

    const int s = seg * 2048 + tid * 8;                  // 8 positions
    const unsigned short* yb = y + (size_t)b * OCH * SPATIAL + s;

    uint4 v[OCH];
#pragma unroll
    for (int c = 0; c < OCH; c++) {
        v[c] = *(const uint4*)(yb + (size_t)c * SPATIAL);
    }

    const float4* pb = prm + b * OCH;

    float mx[8];
#pragma unroll
    for (int j = 0; j < 8; j++) mx[j] = -INFINITY;

#pragma unroll
    for (int c = 0; c < OCH; c++) {
        const float4 p = pb[c];          // wave-uniform addr
        const float A = p.x, Bv = p.y, L = p.z, H = p.w;
        union { uint4 u4; unsigned int u[4]; } vv; vv.u4 = v[c];
#pragma unroll
        for (int w = 0; w < 4; w++) {
            union { unsigned int u; __fp16 h[2]; } a; a.u = vv.u[w];
            float f0 = fmaf((float)a.h[0], A, Bv);
            float f1 = fmaf((float)a.h[1], A, Bv);
            f0 = fminf(fmaxf(f0, L), H);                 // v_med3_f32 idiom
            f1 = fminf(fmaxf(f1, L), H);
            mx[2 * w]     = fmaxf(mx[2 * w],     f0);
            mx[2 * w + 1] = fmaxf(mx[2 * w + 1], f1);
        }
    }

    float* ob = out + (size_t)b * SPATIAL + s;
    float4 o0, o1;
    o0.x = mx[0]; o0.y = mx[1]; o0.z = mx[2]; o0.w = mx[3];
    o1.x = mx[4]; o1.y = mx[5]; o1.z = mx[6]; o1.w = mx[7];
    *(float4*)ob       = o0;
    *(float4*)(ob + 4) = o1;
}

extern "C" void kernel_launch(void* const* d_in, const int* in_sizes, int n_in,
                              void* d_out, int out_size, void* d_ws, size_t ws_size,
                              hipStream_t stream) {
    const float* x    = (const float*)d_in[0];
    const float* cw   = (const float*)d_in[1];
    const float* cb   = (const float*)d_in[2];
    const float* mult = (const float*)d_in[3];
    float* out = (float*)d_out;

    // ws: y fp16 channel-major (64 MB) | stats partials (256 KB) | prm (8 KB) | wt (5.2 KB)
    unsigned short* y = (unsigned short*)d_ws;
    float* stats = (float*)((char*)d_ws + (size_t)NB * OCH * SPATIAL * sizeof(unsigned short));
    float4* prm  = (float4*)(stats + NB * OD * OCH * 2);
    float* wt    = (float*)(prm + NB * OCH);

    transpose_w_kernel<<<6, 256, 0, stream>>>(cw, wt);
    conv_stats_kernel<<<NB * 32, 256, 0, stream>>>(x, wt, cb, mult, y, stats);
    params_kernel<<<8, 256, 0, stream>>>(stats, mult, prm);
    norm_max_kernel<<<NB * 8, 256, 0, stream>>>(y, prm, out);
}

// Round 5
// 137.655 us; speedup vs baseline: 1.4856x; 1.0795x over previous
//
#include <hip/hip_runtime.h>
#include <hip/hip_bf16.h>
#include <math.h>

#define ICH   3
#define OCH   16
#define ID    18
#define IH    34
#define IW    34
#define OD    16
#define OH    32
#define OW    32
#define NB    128
#define SPATIAL  (OD * OH * OW)     // 16384 per (b,c)
#define EPSV     1e-5f

typedef __fp16 fp16x2 __attribute__((ext_vector_type(2)));

// Budget (R3/R4): conv 63.5 (VALU-ISSUE-bound: busy ~40.6us ~= inst model;
// idle ~23us structural, occupancy-independent per R4) | norm 11 (BW
// roofline) | tiny 2 | fixed harness ~67. This round: cut conv inst count
// ~2x via v_dot2_f32_f16 (2 fp16 MACs/inst, fp32 accumulate). 27 taps-rows
// paired (13 pairs + zero-pad); weights prepacked as fp16x2.

// Pre-pass: pack weights into fp16 row-pairs: wp[p][kw][c] = (w[2p],w[2p+1])
// where row r = ic*9 + kd*3 + kh (0..26), r=27 -> 0. u32-packed half2.
__global__ void transpose_w_kernel(const float* __restrict__ cw,
                                   unsigned int* __restrict__ wp) {
    const int i = blockIdx.x * 256 + threadIdx.x;   // 0..671
    if (i < 14 * 48) {
        const int p = i / 48, rem = i - p * 48;
        const int kw = rem >> 4, c = rem & 15;
        const int r0 = 2 * p, r1 = 2 * p + 1;
        // cw is OIDHW: [oc][ic][kd][kh][kw]
        const int ic0 = r0 / 9, kd0 = (r0 / 3) % 3, kh0 = r0 % 3;
        float f0 = cw[((c * ICH + ic0) * 3 + kd0) * 9 + kh0 * 3 + kw];
        float f1 = 0.0f;
        if (r1 < 27) {
            const int ic1 = r1 / 9, kd1 = (r1 / 3) % 3, kh1 = r1 % 3;
            f1 = cw[((c * ICH + ic1) * 3 + kd1) * 9 + kh1 * 3 + kw];
        }
        fp16x2 hv; hv.x = (__fp16)f0; hv.y = (__fp16)f1;
        union { fp16x2 h; unsigned int u; } uu; uu.h = hv;
        wp[i] = uu.u;
    }
}

// ===== conv v11: dot2 conv. 16 ch/block, grid 2048, LB(256,2), channel-
// major y (all best-known R1 settings). Inner math: per row-pair p, per
// (kw,c,out j): acc = fdot2((xA[kw+j],xB[kw+j]), (wA,wB), acc).
// fp32 accumulation -> numerics ~= fp32 conv + fp16 input rounding (5e-4).
// Do NOT: LDS-stage x (R1-R8), MFMA im2col (R13), occupancy pushes (R4:
// occupancy is NOT the limiter), channel-last y (R2: +4.3us).
__global__ __launch_bounds__(256, 2) void conv_stats_kernel(
    const float* __restrict__ x, const unsigned int* __restrict__ wp,
    const float* __restrict__ cb, const float* __restrict__ mult,
    unsigned short* __restrict__ y, float* __restrict__ stats)
{
    __shared__ float wsum[4][OCH], wsq[4][OCH];

    const int blk = blockIdx.x;
    const int b = blk >> 4;
    const int d = blk & 15;
    const int tid = threadIdx.x;

    const int h  = tid >> 3;        // 0..31
    const int wq = (tid & 7) << 2;  // 0,4,...,28

    float acc[OCH][4];
#pragma unroll
    for (int c = 0; c < OCH; c++) {
        const float bv = cb[c];
        acc[c][0] = bv; acc[c][1] = bv; acc[c][2] = bv; acc[c][3] = bv;
    }

    // load one x row (6 floats) and convert to fp16 scalars
#define LOADROW(dst_, plane_, kh_)                                          \
    {                                                                       \
        const float* row_ = (plane_) + (size_t)(h + (kh_)) * IW + wq;       \
        const float4 v0_ = *(const float4*)row_;                            \
        const float2 v1_ = *(const float2*)(row_ + 4);                      \
        dst_[0] = (__fp16)v0_.x; dst_[1] = (__fp16)v0_.y;                   \
        dst_[2] = (__fp16)v0_.z; dst_[3] = (__fp16)v0_.w;                   \
        dst_[4] = (__fp16)v1_.x; dst_[5] = (__fp16)v1_.y;                   \
    }

    // one row-pair: pack 6 columns, then 3kw x 16c x 4out fdot2
#define PAIR(A_, B_, p_)                                                    \
    {                                                                       \
        fp16x2 pk_[6];                                                      \
        _Pragma("unroll")                                                   \
        for (int j_ = 0; j_ < 6; j_++) { pk_[j_].x = A_[j_]; pk_[j_].y = B_[j_]; } \
        const unsigned int* wg_ = wp + (p_) * 48;                           \
        _Pragma("unroll")                                                   \
        for (int kw_ = 0; kw_ < 3; kw_++) {                                 \
            _Pragma("unroll")                                               \
            for (int c_ = 0; c_ < OCH; c_++) {                              \
                union { unsigned int u; fp16x2 h; } wv_;                    \
                wv_.u = wg_[kw_ * OCH + c_];                                \
                acc[c_][0] = __builtin_amdgcn_fdot2(pk_[kw_ + 0], wv_.h, acc[c_][0], false); \
                acc[c_][1] = __builtin_amdgcn_fdot2(pk_[kw_ + 1], wv_.h, acc[c_][1], false); \
                acc[c_][2] = __builtin_amdgcn_fdot2(pk_[kw_ + 2], wv_.h, acc[c_][2], false); \
                acc[c_][3] = __builtin_amdgcn_fdot2(pk_[kw_ + 3], wv_.h, acc[c_][3], false); \
            }                                                               \
        }                                                                   \
    }

    __fp16 pend[6];
#pragma unroll
    for (int g = 0; g < 9; g++) {            // g = ic*3 + kd, rows 3g..3g+2
        const int ic = g / 3, kd = g % 3;
        const float* plane = x + ((size_t)(b * ICH + ic) * ID + (d + kd)) * (IH * IW);
        __fp16 r0[6], r1[6], r2[6];
        LOADROW(r0, plane, 0)
        LOADROW(r1, plane, 1)
        LOADROW(r2, plane, 2)
        if ((g & 1) == 0) {                  // compile-time parity (unrolled)
            PAIR(r0, r1, (3 * g) / 2)
#pragma unroll
            for (int j = 0; j < 6; j++) pend[j] = r2[j];
        } else {
            PAIR(pend, r0, (3 * g - 1) / 2)
            PAIR(r1, r2, (3 * g + 1) / 2)
        }
    }
    {   // final pair: row 26 with zero row (p = 13)
        __fp16 rz[6];
#pragma unroll
        for (int j = 0; j < 6; j++) rz[j] = (__fp16)0.0f;
        PAIR(pend, rz, 13)
    }
#undef PAIR
#undef LOADROW

    // ---- multiplier fold, stats, fp16 store (channel-major, uint2) ----
    float ssum[OCH], ssq[OCH];
#pragma unroll
    for (int c = 0; c < OCH; c++) {
        const float m = mult[c];
        const float o0 = acc[c][0] * m, o1 = acc[c][1] * m;
        const float o2 = acc[c][2] * m, o3 = acc[c][3] * m;
        ssum[c] = (o0 + o1) + (o2 + o3);
        ssq[c]  = (o0 * o0 + o1 * o1) + (o2 * o2 + o3 * o3);
        const size_t yi = ((size_t)(b * OCH + c) * OD + d) * (OH * OW) + h * OW + wq;
        union { fp16x2 h; unsigned int u; } p01, p23;
        p01.h = __builtin_amdgcn_cvt_pkrtz(o0, o1);
        p23.h = __builtin_amdgcn_cvt_pkrtz(o2, o3);
        uint2 pk; pk.x = p01.u; pk.y = p23.u;
        *(uint2*)&y[yi] = pk;
    }

    // ---- block reduction of stats, per-block partial write (no atomics) ----
#pragma unroll
    for (int c = 0; c < OCH; c++) {
        for (int off = 32; off > 0; off >>= 1) {
            ssum[c] += __shfl_down(ssum[c], off);
            ssq[c]  += __shfl_down(ssq[c], off);
        }
    }
    const int wave = tid >> 6, lane = tid & 63;
    if (lane == 0) {
#pragma unroll
        for (int c = 0; c < OCH; c++) { wsum[wave][c] = ssum[c]; wsq[wave][c] = ssq[c]; }
    }
    __syncthreads();
    if (tid < OCH) {
        float s = 0.0f, q = 0.0f;
#pragma unroll
        for (int k = 0; k < 4; k++) { s += wsum[k][tid]; q += wsq[k][tid]; }
        const int sbase = ((b * OD + d) * OCH + tid) * 2;
        stats[sbase + 0] = s;
        stats[sbase + 1] = q;
    }
}

// ===== per-(b,c) norm params: {A = rs*m, B = -mean*rs*m, L = -|m|, H = +|m|}
__global__ void params_kernel(const float* __restrict__ stats,
                              const float* __restrict__ mult,
                              float4* __restrict__ prm)
{
    const int i = blockIdx.x * 256 + threadIdx.x;   // (b,c) pair
    if (i < NB * OCH) {
        const int b = i >> 4, c = i & 15;
        float s = 0.0f, q = 0.0f;
        for (int dd = 0; dd < OD; dd++) {
            s += stats[((b * OD + dd) * OCH + c) * 2 + 0];
            q += stats[((b * OD + dd) * OCH + c) * 2 + 1];
        }
        const float mean = s * (1.0f / (float)SPATIAL);
        float var = q * (1.0f / (float)SPATIAL) - mean * mean;
        var = fmaxf(var, 0.0f);
        const float rs = rsqrtf(var + EPSV);
        const float m  = mult[c];
        float4 p;
        p.x = rs * m;             // A
        p.y = -mean * rs * m;     // B
        p.z = -fabsf(m);          // L
        p.w =  fabsf(m);          // H
        prm[i] = p;
    }
}

// ===== norm_max (R1 version, measured ~11us = BW roofline; do not touch).
__global__ __launch_bounds__(256, 4) void norm_max_kernel(
    const unsigned short* __restrict__ y, const float4* __restrict__ prm,
    float* __restrict__ out)
{
    const int blk = blockIdx.x;     // NB*8 = 1024
    const int b   = blk >> 3;
    const int seg = blk & 7;
    const int tid = threadIdx.x;

    const int s = seg * 2048 + tid * 8;                  // 8 positions
    const unsigned short* yb = y + (size_t)b * OCH * SPATIAL + s;

    uint4 v[OCH];
#pragma unroll
    for (int c = 0; c < OCH; c++) {
        v[c] = *(const uint4*)(yb + (size_t)c * SPATIAL);
    }

    const float4* pb = prm + b * OCH;

    float mx[8];
#pragma unroll
    for (int j = 0; j < 8; j++) mx[j] = -INFINITY;

#pragma unroll
    for (int c = 0; c < OCH; c++) {
        const float4 p = pb[c];          // wave-uniform addr
        const float A = p.x, Bv = p.y, L = p.z, H = p.w;
        union { uint4 u4; unsigned int u[4]; } vv; vv.u4 = v[c];
#pragma unroll
        for (int w = 0; w < 4; w++) {
            union { unsigned int u; __fp16 h[2]; } a; a.u = vv.u[w];
            float f0 = fmaf((float)a.h[0], A, Bv);
            float f1 = fmaf((float)a.h[1], A, Bv);
            f0 = fminf(fmaxf(f0, L), H);                 // v_med3_f32 idiom
            f1 = fminf(fmaxf(f1, L), H);
            mx[2 * w]     = fmaxf(mx[2 * w],     f0);
            mx[2 * w + 1] = fmaxf(mx[2 * w + 1], f1);
        }
    }

    float* ob = out + (size_t)b * SPATIAL + s;
    float4 o0, o1;
    o0.x = mx[0]; o0.y = mx[1]; o0.z = mx[2]; o0.w = mx[3];
    o1.x = mx[4]; o1.y = mx[5]; o1.z = mx[6]; o1.w = mx[7];
    *(float4*)ob       = o0;
    *(float4*)(ob + 4) = o1;
}

extern "C" void kernel_launch(void* const* d_in, const int* in_sizes, int n_in,
                              void* d_out, int out_size, void* d_ws, size_t ws_size,
                              hipStream_t stream) {
    const float* x    = (const float*)d_in[0];
    const float* cw   = (const float*)d_in[1];
    const float* cb   = (const float*)d_in[2];
    const float* mult = (const float*)d_in[3];
    float* out = (float*)d_out;

    // ws: y fp16 channel-major (64 MB) | stats partials (256 KB) | prm (8 KB) | wp (2.7 KB)
    unsigned short* y = (unsigned short*)d_ws;
    float* stats = (float*)((char*)d_ws + (size_t)NB * OCH * SPATIAL * sizeof(unsigned short));
    float4* prm  = (float4*)(stats + NB * OD * OCH * 2);
    unsigned int* wpk = (unsigned int*)(prm + NB * OCH);

    transpose_w_kernel<<<3, 256, 0, stream>>>(cw, wpk);
    conv_stats_kernel<<<NB * 16, 256, 0, stream>>>(x, wpk, cb, mult, y, stats);
    params_kernel<<<8, 256, 0, stream>>>(stats, mult, prm);
    norm_max_kernel<<<NB * 8, 256, 0, stream>>>(y, prm, out);
}